// Round 3
// baseline (611.458 us; speedup 1.0000x reference)
//
#include <hip/hip_runtime.h>
#include <hip/hip_bf16.h>
#include <string.h>

// Batched GEMM: out[b,o,f] = sum_i W[b,o,i] * x[b,i,f]
// B=32, M(O)=1024, K(I)=1024, N(F)=2048, fp32 in/out, bf16 MFMA compute.
//
// Round-2 structure:
//  - A (W) loaded DIRECTLY global->reg->bf16 frag (k-contiguous rows) — no LDS.
//  - B (x) transposed through LDS: [n][k] bf16 rows, stride 40 ushorts (pad+8),
//    XOR swizzle k ^= 8*((n>>3)&3). Both write (b128) and frag read (b128) are
//    2-way-per-bank max (free per m136).
//  - Double-buffered B tile, one __syncthreads per K-step, next-tile global
//    loads issued under current-tile MFMA.

typedef float  f32x2 __attribute__((ext_vector_type(2)));
typedef float  f32x4 __attribute__((ext_vector_type(4)));
typedef short  bf16x8 __attribute__((ext_vector_type(8)));
typedef unsigned int u32;

#define BATCH 32
#define MDIM 1024
#define KDIM 1024
#define NDIM 2048
#define BM 128
#define BN 128
#define BK 32
#define NT (KDIM / BK)   // 32 K-steps
#define BSTRIDE 40       // ushorts per n-row: 32 data + 8 pad

__device__ __forceinline__ u32 cvt2(float a, float b) {
    float2 t; t.x = a; t.y = b;
    __hip_bfloat162 h = __float22bfloat162_rn(t);   // v_cvt_pk_bf16_f32 (RTNE)
    u32 r; memcpy(&r, &h, 4);
    return r;
}

__device__ __forceinline__ void stage_B(unsigned short* __restrict__ buf,
                                        const f32x2* bb, const int* wr_addr) {
    #pragma unroll
    for (int c = 0; c < 2; ++c) {
        u32 p0 = cvt2(bb[0][c], bb[1][c]);
        u32 p1 = cvt2(bb[2][c], bb[3][c]);
        u32 p2 = cvt2(bb[4][c], bb[5][c]);
        u32 p3 = cvt2(bb[6][c], bb[7][c]);
        uint4 v = make_uint4(p0, p1, p2, p3);
        *reinterpret_cast<uint4*>(&buf[wr_addr[c]]) = v;   // ds_write_b128
    }
}

__device__ __forceinline__ void cvt_A(bf16x8* af, const f32x4 aa[4][2]) {
    #pragma unroll
    for (int mi = 0; mi < 4; ++mi) {
        u32 q0 = cvt2(aa[mi][0][0], aa[mi][0][1]);
        u32 q1 = cvt2(aa[mi][0][2], aa[mi][0][3]);
        u32 q2 = cvt2(aa[mi][1][0], aa[mi][1][1]);
        u32 q3 = cvt2(aa[mi][1][2], aa[mi][1][3]);
        uint4 v = make_uint4(q0, q1, q2, q3);
        memcpy(&af[mi], &v, 16);
    }
}

__global__ __launch_bounds__(256) void bgemm_bf16_kernel(
    const float* __restrict__ x, const float* __restrict__ w,
    float* __restrict__ out)
{
    __shared__ unsigned short Bb[2][BN * BSTRIDE];   // 2 x 10240 ushorts = 40 KB? no: 2*128*40*2B = 20 KB

    const int tid = threadIdx.x;
    const int b   = blockIdx.z;
    const int m0  = blockIdx.y * BM;
    const int n0  = blockIdx.x * BN;

    const int lane = tid & 63;
    const int wid  = tid >> 6;
    const int wm   = (wid >> 1) * 64;
    const int wn   = (wid & 1)  * 64;
    const int l15  = lane & 15;
    const int kg8  = (lane >> 4) * 8;

    const float* Ag = w + (size_t)b * MDIM * KDIM + (size_t)m0 * KDIM;
    const float* Bg = x + (size_t)b * KDIM * NDIM + n0;
    float*       Cg = out + (size_t)b * MDIM * NDIM + (size_t)m0 * NDIM + n0;

    // ---- B staging mapping: thread -> 8 k-rows (bk0..bk0+7) x 2 n-cols ----
    const int bn0 = 2 * (tid & 63);
    const int bk0 = (tid >> 6) * 8;
    const float* Bst = Bg + bn0;

    int wr_addr[2];
    #pragma unroll
    for (int c = 0; c < 2; ++c) {
        int n = bn0 + c;
        wr_addr[c] = n * BSTRIDE + ((8 * (tid >> 6)) ^ (8 * ((n >> 3) & 3)));
    }
    int rd_addr[4];
    #pragma unroll
    for (int ni = 0; ni < 4; ++ni) {
        int n = wn + ni * 16 + l15;
        rd_addr[ni] = n * BSTRIDE + (kg8 ^ (8 * ((n >> 3) & 3)));
    }

    // ---- A fragment row pointers (direct global, k-contiguous) ----
    const float* Arow[4];
    #pragma unroll
    for (int mi = 0; mi < 4; ++mi)
        Arow[mi] = Ag + (size_t)(wm + mi * 16 + l15) * KDIM + kg8;

    f32x4 acc[4][4];
    #pragma unroll
    for (int i = 0; i < 4; ++i)
        #pragma unroll
        for (int j = 0; j < 4; ++j)
            acc[i][j] = f32x4{0.f, 0.f, 0.f, 0.f};

    f32x2 bb[8];
    f32x4 aa[4][2];

    // ---- prologue: tile 0 ----
    #pragma unroll
    for (int j = 0; j < 8; ++j)
        bb[j] = *reinterpret_cast<const f32x2*>(Bst + (size_t)(bk0 + j) * NDIM);
    #pragma unroll
    for (int mi = 0; mi < 4; ++mi) {
        aa[mi][0] = *reinterpret_cast<const f32x4*>(Arow[mi]);
        aa[mi][1] = *reinterpret_cast<const f32x4*>(Arow[mi] + 4);
    }
    stage_B(Bb[0], bb, wr_addr);
    #pragma unroll
    for (int j = 0; j < 8; ++j)   // B tile 1 into regs
        bb[j] = *reinterpret_cast<const f32x2*>(Bst + (size_t)(BK + bk0 + j) * NDIM);
    __syncthreads();

    // ---- main loop: t = 0..NT-2 (full pipeline) ----
    for (int t = 0; t < NT - 1; ++t) {
        const int cur = t & 1;
        bf16x8 af[4], bf[4];

        cvt_A(af, aa);                                  // frags for tile t
        stage_B(Bb[cur ^ 1], bb, wr_addr);              // stage tile t+1

        // issue loads: A(t+1), B(t+2) (clamped; last values unused)
        const int ka = (t + 1) * BK;
        #pragma unroll
        for (int mi = 0; mi < 4; ++mi) {
            aa[mi][0] = *reinterpret_cast<const f32x4*>(Arow[mi] + ka);
            aa[mi][1] = *reinterpret_cast<const f32x4*>(Arow[mi] + ka + 4);
        }
        int kb = (t + 2) * BK; if (kb > KDIM - BK) kb = KDIM - BK;
        #pragma unroll
        for (int j = 0; j < 8; ++j)
            bb[j] = *reinterpret_cast<const f32x2*>(Bst + (size_t)(kb + bk0 + j) * NDIM);

        // consume tile t
        #pragma unroll
        for (int ni = 0; ni < 4; ++ni)
            bf[ni] = *reinterpret_cast<const bf16x8*>(&Bb[cur][rd_addr[ni]]);
        #pragma unroll
        for (int mi = 0; mi < 4; ++mi)
            #pragma unroll
            for (int ni = 0; ni < 4; ++ni)
                acc[mi][ni] = __builtin_amdgcn_mfma_f32_16x16x32_bf16(
                    af[mi], bf[ni], acc[mi][ni], 0, 0, 0);

        __syncthreads();
    }

    // ---- epilogue iteration: tile NT-1 (no staging) ----
    {
        const int cur = (NT - 1) & 1;
        bf16x8 af[4], bf[4];
        cvt_A(af, aa);
        #pragma unroll
        for (int ni = 0; ni < 4; ++ni)
            bf[ni] = *reinterpret_cast<const bf16x8*>(&Bb[cur][rd_addr[ni]]);
        #pragma unroll
        for (int mi = 0; mi < 4; ++mi)
            #pragma unroll
            for (int ni = 0; ni < 4; ++ni)
                acc[mi][ni] = __builtin_amdgcn_mfma_f32_16x16x32_bf16(
                    af[mi], bf[ni], acc[mi][ni], 0, 0, 0);
    }

    // ---- C store: D layout col=lane&15, row=(lane>>4)*4+reg ----
    const int rbase = (lane >> 4) * 4;
    #pragma unroll
    for (int mi = 0; mi < 4; ++mi) {
        #pragma unroll
        for (int ni = 0; ni < 4; ++ni) {
            int n  = wn + ni * 16 + l15;
            int mb = wm + mi * 16 + rbase;
            #pragma unroll
            for (int r = 0; r < 4; ++r)
                Cg[(size_t)(mb + r) * NDIM + n] = acc[mi][ni][r];
        }
    }
}

extern "C" void kernel_launch(void* const* d_in, const int* in_sizes, int n_in,
                              void* d_out, int out_size, void* d_ws, size_t ws_size,
                              hipStream_t stream) {
    const float* x = (const float*)d_in[0];   // [32][1024][2048]
    const float* w = (const float*)d_in[1];   // [32][1024][1024]
    float* out = (float*)d_out;               // [32][1024][2048]
    dim3 grid(NDIM / BN, MDIM / BM, BATCH);
    bgemm_bf16_kernel<<<grid, dim3(256), 0, stream>>>(x, w, out);
}

// Round 4
// 258.098 us; speedup vs baseline: 2.3691x; 2.3691x over previous
//
#include <hip/hip_runtime.h>
#include <hip/hip_bf16.h>
#include <string.h>

// Batched GEMM: out[b,o,f] = sum_i W[b,o,i] * x[b,i,f]
// B=32, M(O)=1024, K(I)=1024, N(F)=2048, fp32 in/out, bf16 MFMA compute.
//
// Round-4 structure: 256x256 tile, 512 threads (8 waves, wave tile 128x64),
// BK=32. BOTH operands staged coalesced global->reg->cvt->LDS (round-3's
// direct-global A was a 16-transaction/instr scatter — reverted).
// LDS rows stride 40 ushorts + XOR swizzle k^=8*((row>>3)&3): <=2-way banks
// on writes and frag reads. Double-buffered, one barrier per K-step,
// t+2 global loads issued under tile-t MFMA.

typedef float  f32x2 __attribute__((ext_vector_type(2)));
typedef float  f32x4 __attribute__((ext_vector_type(4)));
typedef short  bf16x8 __attribute__((ext_vector_type(8)));
typedef unsigned int u32;

#define BATCH 32
#define MDIM 1024
#define KDIM 1024
#define NDIM 2048
#define BM 256
#define BN 256
#define BK 32
#define NT (KDIM / BK)   // 32 K-steps
#define LSTR 40          // ushorts per LDS row: 32 data + 8 pad

__device__ __forceinline__ u32 cvt2(float a, float b) {
    float2 t; t.x = a; t.y = b;
    __hip_bfloat162 h = __float22bfloat162_rn(t);   // v_cvt_pk_bf16_f32 (RTNE)
    u32 r; memcpy(&r, &h, 4);
    return r;
}

__device__ __forceinline__ int swz(int row) { return 8 * ((row >> 3) & 3); }

__global__ __launch_bounds__(512, 2) void bgemm_bf16_kernel(
    const float* __restrict__ x, const float* __restrict__ w,
    float* __restrict__ out)
{
    __shared__ unsigned short Ab[2][BM * LSTR];   // W tile  [m][k]  40 KB
    __shared__ unsigned short Bb[2][BN * LSTR];   // x tile^T [n][k] 40 KB

    const int tid = threadIdx.x;
    const int b   = blockIdx.z;
    const int m0  = blockIdx.y * BM;
    const int n0  = blockIdx.x * BN;

    const int lane = tid & 63;
    const int wid  = tid >> 6;
    const int wm   = (wid >> 2) * 128;   // wave tile 128x64
    const int wn   = (wid & 3)  * 64;
    const int l15  = lane & 15;
    const int kg8  = (lane >> 4) * 8;

    const float* Ag = w + (size_t)b * MDIM * KDIM + (size_t)m0 * KDIM;
    const float* Bg = x + (size_t)b * KDIM * NDIM + n0;
    float*       Cg = out + (size_t)b * MDIM * NDIM + (size_t)m0 * NDIM + n0;

    // ---- A staging map: thread -> rows (tid>>3)+64i, f32x4 col tid&7 ----
    const int a_k4 = tid & 7;
    const int a_m0 = tid >> 3;           // 0..63
    int a_idx[4];
    #pragma unroll
    for (int i = 0; i < 4; ++i) {
        int m = a_m0 + 64 * i;
        a_idx[i] = m * LSTR + ((4 * a_k4) ^ swz(m));
    }
    // ---- B staging map: thread -> k rows 8*(tid>>7)+j, n cols 2*(tid&127) ----
    const int bn0  = 2 * (tid & 127);
    const int b_k0 = 8 * (tid >> 7);     // 0,8,16,24
    int b_idx[2];
    #pragma unroll
    for (int c = 0; c < 2; ++c) {
        int n = bn0 + c;
        b_idx[c] = n * LSTR + (b_k0 ^ swz(n));
    }
    // ---- frag read addrs ----
    int rd_a[8], rd_b[4];
    #pragma unroll
    for (int mi = 0; mi < 8; ++mi) {
        int m = wm + mi * 16 + l15;
        rd_a[mi] = m * LSTR + (kg8 ^ swz(m));
    }
    #pragma unroll
    for (int ni = 0; ni < 4; ++ni) {
        int n = wn + ni * 16 + l15;
        rd_b[ni] = n * LSTR + (kg8 ^ swz(n));
    }

    const float* Ap = Ag + (size_t)a_m0 * KDIM + 4 * a_k4;
    const float* Bp = Bg + (size_t)b_k0 * NDIM + bn0;

    f32x4 acc[8][4];
    #pragma unroll
    for (int i = 0; i < 8; ++i)
        #pragma unroll
        for (int j = 0; j < 4; ++j)
            acc[i][j] = f32x4{0.f, 0.f, 0.f, 0.f};

    f32x4 aav[4];
    f32x2 bbv[8];

    // ---- loads of K-step kt into regs ----
    auto load_regs = [&](int kt) {
        #pragma unroll
        for (int i = 0; i < 4; ++i)
            aav[i] = *reinterpret_cast<const f32x4*>(Ap + (size_t)(64 * i) * KDIM + kt);
        #pragma unroll
        for (int j = 0; j < 8; ++j)
            bbv[j] = *reinterpret_cast<const f32x2*>(Bp + (size_t)(kt + j) * NDIM);
    };
    // ---- cvt + LDS write of reg tile into buffer s ----
    auto stage = [&](int s) {
        #pragma unroll
        for (int i = 0; i < 4; ++i) {
            uint2 v = make_uint2(cvt2(aav[i][0], aav[i][1]),
                                 cvt2(aav[i][2], aav[i][3]));
            *reinterpret_cast<uint2*>(&Ab[s][a_idx[i]]) = v;   // ds_write_b64
        }
        #pragma unroll
        for (int c = 0; c < 2; ++c) {
            uint4 v = make_uint4(cvt2(bbv[0][c], bbv[1][c]),
                                 cvt2(bbv[2][c], bbv[3][c]),
                                 cvt2(bbv[4][c], bbv[5][c]),
                                 cvt2(bbv[6][c], bbv[7][c]));
            *reinterpret_cast<uint4*>(&Bb[s][b_idx[c]]) = v;   // ds_write_b128
        }
    };
    // ---- frag reads + 32 MFMA on buffer s ----
    auto compute = [&](int s) {
        bf16x8 bfr[4];
        #pragma unroll
        for (int ni = 0; ni < 4; ++ni)
            bfr[ni] = *reinterpret_cast<const bf16x8*>(&Bb[s][rd_b[ni]]);
        #pragma unroll
        for (int mi = 0; mi < 8; ++mi) {
            bf16x8 af = *reinterpret_cast<const bf16x8*>(&Ab[s][rd_a[mi]]);
            #pragma unroll
            for (int ni = 0; ni < 4; ++ni)
                acc[mi][ni] = __builtin_amdgcn_mfma_f32_16x16x32_bf16(
                    af, bfr[ni], acc[mi][ni], 0, 0, 0);
        }
    };

    // ---- prologue ----
    load_regs(0);
    stage(0);
    load_regs(BK);
    __syncthreads();

    // ---- main loop ----
    for (int t = 0; t < NT - 1; ++t) {
        const int cur = t & 1;
        stage(cur ^ 1);                       // tile t+1 -> other buffer
        int kt2 = (t + 2) * BK;               // issue loads for t+2
        if (kt2 > KDIM - BK) kt2 = KDIM - BK; // clamp (redundant, harmless)
        load_regs(kt2);
        compute(cur);                         // tile t
        __syncthreads();
    }
    compute((NT - 1) & 1);                    // last tile

    // ---- C store: D layout col=lane&15, row=(lane>>4)*4+reg ----
    const int rbase = (lane >> 4) * 4;
    #pragma unroll
    for (int mi = 0; mi < 8; ++mi) {
        #pragma unroll
        for (int ni = 0; ni < 4; ++ni) {
            int n  = wn + ni * 16 + l15;
            int mb = wm + mi * 16 + rbase;
            #pragma unroll
            for (int r = 0; r < 4; ++r)
                Cg[(size_t)(mb + r) * NDIM + n] = acc[mi][ni][r];
        }
    }
}

extern "C" void kernel_launch(void* const* d_in, const int* in_sizes, int n_in,
                              void* d_out, int out_size, void* d_ws, size_t ws_size,
                              hipStream_t stream) {
    const float* x = (const float*)d_in[0];   // [32][1024][2048]
    const float* w = (const float*)d_in[1];   // [32][1024][1024]
    float* out = (float*)d_out;               // [32][1024][2048]
    dim3 grid(NDIM / BN, MDIM / BM, BATCH);
    bgemm_bf16_kernel<<<grid, dim3(512), 0, stream>>>(x, w, out);
}